// Round 8
// baseline (81.773 us; speedup 1.0000x reference)
//
#include <hip/hip_runtime.h>
#include <hip/hip_bf16.h>

// Problem: B=4, T=256, U=65, D=512, V=1024, fp32.
// out[b,t,u,v] = encP[b,t,v] + decP[b,u,v]
//   encP = gelu_tanh(enc) @ W[:, :D]^T   (M=1024, N=1024, K=512)
//   decP = gelu_tanh(dec) @ W[:, D:]^T   (M=260,  N=1024, K=512)

#define B_ 4
#define T_ 256
#define U_ 65
#define D_ 512
#define V_ 1024
#define TB 4       // bt rows per bcast block (divides T_)
#define USPLIT 8   // u-segments per bt tile
#define ULEN 9     // ceil(U_/USPLIT)

typedef __attribute__((ext_vector_type(8))) short bf16x8;   // 8 bf16 = 4 VGPRs
typedef __attribute__((ext_vector_type(4))) float f32x4;

__device__ __forceinline__ float gelu_tanh(float x) {
    const float c = 0.7978845608028654f;  // sqrt(2/pi)
    float x3 = x * x * x;
    float t = tanhf(c * (x + 0.044715f * x3));
    return 0.5f * x * (1.0f + t);
}

__device__ __forceinline__ ushort bf16bits(float x) {
    union { float f; unsigned u; } c; c.f = x;
    unsigned r = c.u + 0x7FFF + ((c.u >> 16) & 1);   // RNE
    return (ushort)(r >> 16);
}

// ---------------------------------------------------------------------------
// Kernel 1: gelu+cast enc/dec to bf16, cast W to bf16.
// float4 loads, single 8B (ushort4) bf16 store per thread.
// ---------------------------------------------------------------------------
__global__ __launch_bounds__(256)
void prep_kernel(const float* __restrict__ enc,
                 const float* __restrict__ dec,
                 const float* __restrict__ W,
                 __hip_bfloat16* __restrict__ geB,
                 __hip_bfloat16* __restrict__ gdB,
                 __hip_bfloat16* __restrict__ WB) {
    const int NE4 = (B_ * T_ * D_) / 4;     // 131072
    const int ND4 = (B_ * U_ * D_) / 4;     // 33280
    const int NW4 = (V_ * 2 * D_) / 4;      // 262144
    int i = blockIdx.x * blockDim.x + threadIdx.x;
    if (i < NE4) {
        float4 v = ((const float4*)enc)[i];
        ushort4 o;
        o.x = bf16bits(gelu_tanh(v.x));
        o.y = bf16bits(gelu_tanh(v.y));
        o.z = bf16bits(gelu_tanh(v.z));
        o.w = bf16bits(gelu_tanh(v.w));
        ((ushort4*)geB)[i] = o;
    } else if (i < NE4 + ND4) {
        int j = i - NE4;
        float4 v = ((const float4*)dec)[j];
        ushort4 o;
        o.x = bf16bits(gelu_tanh(v.x));
        o.y = bf16bits(gelu_tanh(v.y));
        o.z = bf16bits(gelu_tanh(v.z));
        o.w = bf16bits(gelu_tanh(v.w));
        ((ushort4*)gdB)[j] = o;
    } else if (i < NE4 + ND4 + NW4) {
        int j = i - NE4 - ND4;
        float4 v = ((const float4*)W)[j];
        ushort4 o;
        o.x = bf16bits(v.x);
        o.y = bf16bits(v.y);
        o.z = bf16bits(v.z);
        o.w = bf16bits(v.w);
        ((ushort4*)WB)[j] = o;
    }
}

// ---------------------------------------------------------------------------
// Kernel 2: bf16 MFMA GEMM, NT layout, direct global loads (L2-resident data).
// 64x64 tile / 256-thread block; 4 waves 2x2; wave = 2x2 of 16x16x32 frags.
// Explicit 2-deep K pipeline, #pragma unroll 1 (R5 structure, kept constant).
// ---------------------------------------------------------------------------
__global__ __launch_bounds__(256)
void gemm_kernel(const __hip_bfloat16* __restrict__ geB,
                 const __hip_bfloat16* __restrict__ gdB,
                 const __hip_bfloat16* __restrict__ WB,
                 float* __restrict__ encP,
                 float* __restrict__ decP) {
    int blk = blockIdx.x;
    const __hip_bfloat16* A;
    float* C;
    int M, kofs, mt, nt;
    if (blk < 256) {
        A = geB; C = encP; M = B_ * T_; kofs = 0;
        mt = blk >> 4; nt = blk & 15;
    } else {
        blk -= 256;
        A = gdB; C = decP; M = B_ * U_; kofs = D_;
        mt = blk >> 4; nt = blk & 15;
    }
    const int lane = threadIdx.x & 63;
    const int w    = threadIdx.x >> 6;     // 0..3
    const int wr   = w >> 1, wc = w & 1;   // waves 2x2 over the 64x64 tile
    const int r16  = lane & 15;            // A row / B col within fragment
    const int k8   = (lane >> 4) * 8;      // K sub-offset within K=32 step

    const int m_base = mt * 64 + wr * 32;
    const int n_base = nt * 64 + wc * 32;

    const __hip_bfloat16* Arow0 = A + (size_t)((m_base + 0  + r16) < M ? (m_base + 0  + r16) : 0) * D_ + k8;
    const __hip_bfloat16* Arow1 = A + (size_t)((m_base + 16 + r16) < M ? (m_base + 16 + r16) : 0) * D_ + k8;
    const __hip_bfloat16* Brow0 = WB + (size_t)(n_base + 0  + r16) * (2 * D_) + kofs + k8;
    const __hip_bfloat16* Brow1 = WB + (size_t)(n_base + 16 + r16) * (2 * D_) + kofs + k8;

    f32x4 acc[2][2] = {};
    bf16x8 aC0, aC1, bC0, bC1, aN0, aN1, bN0, bN1;

    aC0 = *(const bf16x8*)(Arow0);  aC1 = *(const bf16x8*)(Arow1);
    bC0 = *(const bf16x8*)(Brow0);  bC1 = *(const bf16x8*)(Brow1);

#pragma unroll 1
    for (int k0 = 0; k0 < D_; k0 += 64) {
        aN0 = *(const bf16x8*)(Arow0 + k0 + 32);
        aN1 = *(const bf16x8*)(Arow1 + k0 + 32);
        bN0 = *(const bf16x8*)(Brow0 + k0 + 32);
        bN1 = *(const bf16x8*)(Brow1 + k0 + 32);
        acc[0][0] = __builtin_amdgcn_mfma_f32_16x16x32_bf16(aC0, bC0, acc[0][0], 0, 0, 0);
        acc[0][1] = __builtin_amdgcn_mfma_f32_16x16x32_bf16(aC0, bC1, acc[0][1], 0, 0, 0);
        acc[1][0] = __builtin_amdgcn_mfma_f32_16x16x32_bf16(aC1, bC0, acc[1][0], 0, 0, 0);
        acc[1][1] = __builtin_amdgcn_mfma_f32_16x16x32_bf16(aC1, bC1, acc[1][1], 0, 0, 0);
        if (k0 + 64 < D_) {
            aC0 = *(const bf16x8*)(Arow0 + k0 + 64);
            aC1 = *(const bf16x8*)(Arow1 + k0 + 64);
            bC0 = *(const bf16x8*)(Brow0 + k0 + 64);
            bC1 = *(const bf16x8*)(Brow1 + k0 + 64);
        }
        acc[0][0] = __builtin_amdgcn_mfma_f32_16x16x32_bf16(aN0, bN0, acc[0][0], 0, 0, 0);
        acc[0][1] = __builtin_amdgcn_mfma_f32_16x16x32_bf16(aN0, bN1, acc[0][1], 0, 0, 0);
        acc[1][0] = __builtin_amdgcn_mfma_f32_16x16x32_bf16(aN1, bN0, acc[1][0], 0, 0, 0);
        acc[1][1] = __builtin_amdgcn_mfma_f32_16x16x32_bf16(aN1, bN1, acc[1][1], 0, 0, 0);
    }

    // C/D layout: col = lane&15, row = (lane>>4)*4 + j
    const int c_row0 = (lane >> 4) * 4;
#pragma unroll
    for (int mi = 0; mi < 2; ++mi) {
#pragma unroll
        for (int j = 0; j < 4; ++j) {
            int row = m_base + mi * 16 + c_row0 + j;
            if (row < M) {
#pragma unroll
                for (int ni = 0; ni < 2; ++ni) {
                    int col = n_base + ni * 16 + r16;
                    C[(size_t)row * V_ + col] = acc[mi][ni][j];
                }
            }
        }
    }
}

// ---------------------------------------------------------------------------
// Kernel 3: broadcast add — R7 structure EXACTLY, single change: nontemporal
// stores. Theory: the 272MB write stream write-allocates through L2, evicting
// the encP/decP lines concurrent blocks are about to read (~106MB of reads
// fall to HBM). nt flag = evict-first -> reads stay L2-resident.
// ---------------------------------------------------------------------------
__global__ __launch_bounds__(256)
void bcast_kernel(const float* __restrict__ encP,
                  const float* __restrict__ decP,
                  float* __restrict__ out) {
    const int tid = threadIdx.x;           // 256 threads * f32x4 = V=1024
    const int bt0 = blockIdx.x * TB;
    const int b   = bt0 >> 8;              // T_ = 256
    const int u0  = blockIdx.y * ULEN;
    const int nu  = (u0 + ULEN <= U_) ? ULEN : (U_ - u0);   // 9 or 2

    const f32x4* d4 = (const f32x4*)(decP + (size_t)b * U_ * V_);

    // hoisted loads: all independent, all in flight before the store phase
    f32x4 dv[ULEN];
#pragma unroll
    for (int j = 0; j < ULEN; ++j)
        if (j < nu)
            dv[j] = d4[(size_t)(u0 + j) * (V_ / 4) + tid];

    f32x4 ev[TB];
#pragma unroll
    for (int i = 0; i < TB; ++i)
        ev[i] = ((const f32x4*)(encP + (size_t)(bt0 + i) * V_))[tid];

    f32x4* o4 = (f32x4*)(out + (size_t)bt0 * U_ * V_);

    // pure store phase: 36 x (add + 1KB/wave contiguous NT store)
#pragma unroll
    for (int j = 0; j < ULEN; ++j) {
        if (j < nu) {
#pragma unroll
            for (int i = 0; i < TB; ++i) {
                f32x4 ov = ev[i] + dv[j];
                __builtin_nontemporal_store(ov, &o4[((size_t)i * U_ + (u0 + j)) * (V_ / 4) + tid]);
            }
        }
    }
}

extern "C" void kernel_launch(void* const* d_in, const int* in_sizes, int n_in,
                              void* d_out, int out_size, void* d_ws, size_t ws_size,
                              hipStream_t stream) {
    const float* enc = (const float*)d_in[0];   // (4,256,512)
    const float* dec = (const float*)d_in[1];   // (4,65,512)
    const float* W   = (const float*)d_in[2];   // (1024, 1024)
    float* out = (float*)d_out;                 // (4,256,65,1024)

    char* ws = (char*)d_ws;
    __hip_bfloat16* geB  = (__hip_bfloat16*)(ws);              // 1.00 MB
    __hip_bfloat16* gdB  = (__hip_bfloat16*)(ws + 0x100000);   // 0.26 MB
    __hip_bfloat16* WB   = (__hip_bfloat16*)(ws + 0x180000);   // 2.00 MB
    float*          encP = (float*)(ws + 0x380000);            // 4.00 MB
    float*          decP = (float*)(ws + 0x780000);            // 1.04 MB

    const int total4 = (B_ * T_ * D_ + B_ * U_ * D_ + V_ * 2 * D_) / 4;  // 426496
    prep_kernel<<<(total4 + 255) / 256, 256, 0, stream>>>(enc, dec, W, geB, gdB, WB);
    gemm_kernel<<<256 + 80, 256, 0, stream>>>(geB, gdB, WB, encP, decP);
    dim3 bgrid(T_ * B_ / TB, USPLIT);  // (256, 8) = 2048 blocks
    bcast_kernel<<<bgrid, 256, 0, stream>>>(encP, decP, out);
}

// Round 9
// 71.504 us; speedup vs baseline: 1.1436x; 1.1436x over previous
//
#include <hip/hip_runtime.h>
#include <hip/hip_bf16.h>

// Problem: B=4, T=256, U=65, D=512, V=1024, fp32.
// out[b,t,u,v] = encP[b,t,v] + decP[b,u,v]
//   encP = gelu_tanh(enc) @ W[:, :D]^T   (M=1024, N=1024, K=512)
//   decP = gelu_tanh(dec) @ W[:, D:]^T   (M=260,  N=1024, K=512)

#define B_ 4
#define T_ 256
#define U_ 65
#define D_ 512
#define V_ 1024
#define TB 8       // bt rows per bcast block (divides T_)
#define USPLIT 4   // u-segments per bt tile
#define ULEN 17    // ceil(U_/USPLIT)

typedef __attribute__((ext_vector_type(8))) short bf16x8;   // 8 bf16 = 4 VGPRs
typedef __attribute__((ext_vector_type(4))) float f32x4;

__device__ __forceinline__ float gelu_tanh(float x) {
    const float c = 0.7978845608028654f;  // sqrt(2/pi)
    float x3 = x * x * x;
    float t = tanhf(c * (x + 0.044715f * x3));
    return 0.5f * x * (1.0f + t);
}

__device__ __forceinline__ ushort bf16bits(float x) {
    union { float f; unsigned u; } c; c.f = x;
    unsigned r = c.u + 0x7FFF + ((c.u >> 16) & 1);   // RNE
    return (ushort)(r >> 16);
}

// ---------------------------------------------------------------------------
// Kernel 1: gelu+cast enc/dec to bf16, cast W to bf16.
// float4 loads, single 8B (ushort4) bf16 store per thread.
// ---------------------------------------------------------------------------
__global__ __launch_bounds__(256)
void prep_kernel(const float* __restrict__ enc,
                 const float* __restrict__ dec,
                 const float* __restrict__ W,
                 __hip_bfloat16* __restrict__ geB,
                 __hip_bfloat16* __restrict__ gdB,
                 __hip_bfloat16* __restrict__ WB) {
    const int NE4 = (B_ * T_ * D_) / 4;     // 131072
    const int ND4 = (B_ * U_ * D_) / 4;     // 33280
    const int NW4 = (V_ * 2 * D_) / 4;      // 262144
    int i = blockIdx.x * blockDim.x + threadIdx.x;
    if (i < NE4) {
        float4 v = ((const float4*)enc)[i];
        ushort4 o;
        o.x = bf16bits(gelu_tanh(v.x));
        o.y = bf16bits(gelu_tanh(v.y));
        o.z = bf16bits(gelu_tanh(v.z));
        o.w = bf16bits(gelu_tanh(v.w));
        ((ushort4*)geB)[i] = o;
    } else if (i < NE4 + ND4) {
        int j = i - NE4;
        float4 v = ((const float4*)dec)[j];
        ushort4 o;
        o.x = bf16bits(gelu_tanh(v.x));
        o.y = bf16bits(gelu_tanh(v.y));
        o.z = bf16bits(gelu_tanh(v.z));
        o.w = bf16bits(gelu_tanh(v.w));
        ((ushort4*)gdB)[j] = o;
    } else if (i < NE4 + ND4 + NW4) {
        int j = i - NE4 - ND4;
        float4 v = ((const float4*)W)[j];
        ushort4 o;
        o.x = bf16bits(v.x);
        o.y = bf16bits(v.y);
        o.z = bf16bits(v.z);
        o.w = bf16bits(v.w);
        ((ushort4*)WB)[j] = o;
    }
}

// ---------------------------------------------------------------------------
// Kernel 2: bf16 MFMA GEMM, NT layout, direct global loads (L2-resident data).
// 64x64 tile / 256-thread block; 4 waves 2x2; wave = 2x2 of 16x16x32 frags.
// Explicit 2-deep K pipeline, #pragma unroll 1 (R5 structure, kept constant).
// ---------------------------------------------------------------------------
__global__ __launch_bounds__(256)
void gemm_kernel(const __hip_bfloat16* __restrict__ geB,
                 const __hip_bfloat16* __restrict__ gdB,
                 const __hip_bfloat16* __restrict__ WB,
                 float* __restrict__ encP,
                 float* __restrict__ decP) {
    int blk = blockIdx.x;
    const __hip_bfloat16* A;
    float* C;
    int M, kofs, mt, nt;
    if (blk < 256) {
        A = geB; C = encP; M = B_ * T_; kofs = 0;
        mt = blk >> 4; nt = blk & 15;
    } else {
        blk -= 256;
        A = gdB; C = decP; M = B_ * U_; kofs = D_;
        mt = blk >> 4; nt = blk & 15;
    }
    const int lane = threadIdx.x & 63;
    const int w    = threadIdx.x >> 6;     // 0..3
    const int wr   = w >> 1, wc = w & 1;   // waves 2x2 over the 64x64 tile
    const int r16  = lane & 15;            // A row / B col within fragment
    const int k8   = (lane >> 4) * 8;      // K sub-offset within K=32 step

    const int m_base = mt * 64 + wr * 32;
    const int n_base = nt * 64 + wc * 32;

    const __hip_bfloat16* Arow0 = A + (size_t)((m_base + 0  + r16) < M ? (m_base + 0  + r16) : 0) * D_ + k8;
    const __hip_bfloat16* Arow1 = A + (size_t)((m_base + 16 + r16) < M ? (m_base + 16 + r16) : 0) * D_ + k8;
    const __hip_bfloat16* Brow0 = WB + (size_t)(n_base + 0  + r16) * (2 * D_) + kofs + k8;
    const __hip_bfloat16* Brow1 = WB + (size_t)(n_base + 16 + r16) * (2 * D_) + kofs + k8;

    f32x4 acc[2][2] = {};
    bf16x8 aC0, aC1, bC0, bC1, aN0, aN1, bN0, bN1;

    aC0 = *(const bf16x8*)(Arow0);  aC1 = *(const bf16x8*)(Arow1);
    bC0 = *(const bf16x8*)(Brow0);  bC1 = *(const bf16x8*)(Brow1);

#pragma unroll 1
    for (int k0 = 0; k0 < D_; k0 += 64) {
        aN0 = *(const bf16x8*)(Arow0 + k0 + 32);
        aN1 = *(const bf16x8*)(Arow1 + k0 + 32);
        bN0 = *(const bf16x8*)(Brow0 + k0 + 32);
        bN1 = *(const bf16x8*)(Brow1 + k0 + 32);
        acc[0][0] = __builtin_amdgcn_mfma_f32_16x16x32_bf16(aC0, bC0, acc[0][0], 0, 0, 0);
        acc[0][1] = __builtin_amdgcn_mfma_f32_16x16x32_bf16(aC0, bC1, acc[0][1], 0, 0, 0);
        acc[1][0] = __builtin_amdgcn_mfma_f32_16x16x32_bf16(aC1, bC0, acc[1][0], 0, 0, 0);
        acc[1][1] = __builtin_amdgcn_mfma_f32_16x16x32_bf16(aC1, bC1, acc[1][1], 0, 0, 0);
        if (k0 + 64 < D_) {
            aC0 = *(const bf16x8*)(Arow0 + k0 + 64);
            aC1 = *(const bf16x8*)(Arow1 + k0 + 64);
            bC0 = *(const bf16x8*)(Brow0 + k0 + 64);
            bC1 = *(const bf16x8*)(Brow1 + k0 + 64);
        }
        acc[0][0] = __builtin_amdgcn_mfma_f32_16x16x32_bf16(aN0, bN0, acc[0][0], 0, 0, 0);
        acc[0][1] = __builtin_amdgcn_mfma_f32_16x16x32_bf16(aN0, bN1, acc[0][1], 0, 0, 0);
        acc[1][0] = __builtin_amdgcn_mfma_f32_16x16x32_bf16(aN1, bN0, acc[1][0], 0, 0, 0);
        acc[1][1] = __builtin_amdgcn_mfma_f32_16x16x32_bf16(aN1, bN1, acc[1][1], 0, 0, 0);
    }

    // C/D layout: col = lane&15, row = (lane>>4)*4 + j
    const int c_row0 = (lane >> 4) * 4;
#pragma unroll
    for (int mi = 0; mi < 2; ++mi) {
#pragma unroll
        for (int j = 0; j < 4; ++j) {
            int row = m_base + mi * 16 + c_row0 + j;
            if (row < M) {
#pragma unroll
                for (int ni = 0; ni < 2; ++ni) {
                    int col = n_base + ni * 16 + r16;
                    C[(size_t)row * V_ + col] = acc[mi][ni][j];
                }
            }
        }
    }
}

// ---------------------------------------------------------------------------
// Kernel 3: broadcast add — R7 structure (hoisted loads, pure store phase,
// regular stores), with halved cross-block re-reads: TB=8 (decP re-reads
// 68->34MB), USPLIT=4 (encP re-reads 32->16MB). Grid (128,4) = 512 blocks,
// 2/CU, 8 waves/CU (fill saturates at ~3). Store loop i-outer/j-inner:
// each per-wave stream writes 17 consecutive 4KB rows (68KB sequential).
// ---------------------------------------------------------------------------
__global__ __launch_bounds__(256)
void bcast_kernel(const float* __restrict__ encP,
                  const float* __restrict__ decP,
                  float* __restrict__ out) {
    const int tid = threadIdx.x;           // 256 threads * f32x4 = V=1024
    const int bt0 = blockIdx.x * TB;
    const int b   = bt0 >> 8;              // T_ = 256, TB | 256
    const int u0  = blockIdx.y * ULEN;
    const int nu  = (u0 + ULEN <= U_) ? ULEN : (U_ - u0);   // 17 or 14

    const f32x4* d4 = (const f32x4*)(decP + (size_t)b * U_ * V_);

    // hoisted loads: 17 dv + 8 ev, all independent and in flight before stores
    f32x4 dv[ULEN];
#pragma unroll
    for (int j = 0; j < ULEN; ++j)
        if (j < nu)
            dv[j] = d4[(size_t)(u0 + j) * (V_ / 4) + tid];

    f32x4 ev[TB];
#pragma unroll
    for (int i = 0; i < TB; ++i)
        ev[i] = ((const f32x4*)(encP + (size_t)(bt0 + i) * V_))[tid];

    f32x4* o4 = (f32x4*)(out + (size_t)bt0 * U_ * V_);

    // pure store phase: per (i) stream, nu consecutive 4KB rows
#pragma unroll
    for (int i = 0; i < TB; ++i) {
#pragma unroll
        for (int j = 0; j < ULEN; ++j) {
            if (j < nu) {
                f32x4 ov = ev[i] + dv[j];
                o4[((size_t)i * U_ + (u0 + j)) * (V_ / 4) + tid] = ov;
            }
        }
    }
}

extern "C" void kernel_launch(void* const* d_in, const int* in_sizes, int n_in,
                              void* d_out, int out_size, void* d_ws, size_t ws_size,
                              hipStream_t stream) {
    const float* enc = (const float*)d_in[0];   // (4,256,512)
    const float* dec = (const float*)d_in[1];   // (4,65,512)
    const float* W   = (const float*)d_in[2];   // (1024, 1024)
    float* out = (float*)d_out;                 // (4,256,65,1024)

    char* ws = (char*)d_ws;
    __hip_bfloat16* geB  = (__hip_bfloat16*)(ws);              // 1.00 MB
    __hip_bfloat16* gdB  = (__hip_bfloat16*)(ws + 0x100000);   // 0.26 MB
    __hip_bfloat16* WB   = (__hip_bfloat16*)(ws + 0x180000);   // 2.00 MB
    float*          encP = (float*)(ws + 0x380000);            // 4.00 MB
    float*          decP = (float*)(ws + 0x780000);            // 1.04 MB

    const int total4 = (B_ * T_ * D_ + B_ * U_ * D_ + V_ * 2 * D_) / 4;  // 426496
    prep_kernel<<<(total4 + 255) / 256, 256, 0, stream>>>(enc, dec, W, geB, gdB, WB);
    gemm_kernel<<<256 + 80, 256, 0, stream>>>(geB, gdB, WB, encP, decP);
    dim3 bgrid((B_ * T_) / TB, USPLIT);  // (128, 4) = 512 blocks
    bcast_kernel<<<bgrid, 256, 0, stream>>>(encP, decP, out);
}

// Round 11
// 70.731 us; speedup vs baseline: 1.1561x; 1.0109x over previous
//
#include <hip/hip_runtime.h>
#include <hip/hip_bf16.h>

// Problem: B=4, T=256, U=65, D=512, V=1024, fp32.
// out[b,t,u,v] = encP[b,t,v] + decP[b,u,v]
//   encP = gelu_tanh(enc) @ W[:, :D]^T   (M=1024, N=1024, K=512)
//   decP = gelu_tanh(dec) @ W[:, D:]^T   (M=260,  N=1024, K=512)

#define B_ 4
#define T_ 256
#define U_ 65
#define D_ 512
#define V_ 1024
#define TB 8       // bt rows per bcast block (divides T_)
#define USPLIT 5   // u-segments per bt tile (65 = 5*13, exact)
#define ULEN 13    // U_/USPLIT

typedef __attribute__((ext_vector_type(8))) short bf16x8;   // 8 bf16 = 4 VGPRs
typedef __attribute__((ext_vector_type(4))) float f32x4;

__device__ __forceinline__ float gelu_tanh(float x) {
    const float c = 0.7978845608028654f;  // sqrt(2/pi)
    float x3 = x * x * x;
    float t = tanhf(c * (x + 0.044715f * x3));
    return 0.5f * x * (1.0f + t);
}

__device__ __forceinline__ ushort bf16bits(float x) {
    union { float f; unsigned u; } c; c.f = x;
    unsigned r = c.u + 0x7FFF + ((c.u >> 16) & 1);   // RNE
    return (ushort)(r >> 16);
}

// ---------------------------------------------------------------------------
// Kernel 1: gelu+cast enc/dec to bf16, cast W to bf16.
// float4 loads, single 8B (ushort4) bf16 store per thread.
// ---------------------------------------------------------------------------
__global__ __launch_bounds__(256)
void prep_kernel(const float* __restrict__ enc,
                 const float* __restrict__ dec,
                 const float* __restrict__ W,
                 __hip_bfloat16* __restrict__ geB,
                 __hip_bfloat16* __restrict__ gdB,
                 __hip_bfloat16* __restrict__ WB) {
    const int NE4 = (B_ * T_ * D_) / 4;     // 131072
    const int ND4 = (B_ * U_ * D_) / 4;     // 33280
    const int NW4 = (V_ * 2 * D_) / 4;      // 262144
    int i = blockIdx.x * blockDim.x + threadIdx.x;
    if (i < NE4) {
        float4 v = ((const float4*)enc)[i];
        ushort4 o;
        o.x = bf16bits(gelu_tanh(v.x));
        o.y = bf16bits(gelu_tanh(v.y));
        o.z = bf16bits(gelu_tanh(v.z));
        o.w = bf16bits(gelu_tanh(v.w));
        ((ushort4*)geB)[i] = o;
    } else if (i < NE4 + ND4) {
        int j = i - NE4;
        float4 v = ((const float4*)dec)[j];
        ushort4 o;
        o.x = bf16bits(gelu_tanh(v.x));
        o.y = bf16bits(gelu_tanh(v.y));
        o.z = bf16bits(gelu_tanh(v.z));
        o.w = bf16bits(gelu_tanh(v.w));
        ((ushort4*)gdB)[j] = o;
    } else if (i < NE4 + ND4 + NW4) {
        int j = i - NE4 - ND4;
        float4 v = ((const float4*)W)[j];
        ushort4 o;
        o.x = bf16bits(v.x);
        o.y = bf16bits(v.y);
        o.z = bf16bits(v.z);
        o.w = bf16bits(v.w);
        ((ushort4*)WB)[j] = o;
    }
}

// ---------------------------------------------------------------------------
// Kernel 2: bf16 MFMA GEMM, NT layout, direct global loads (L2-resident data).
// 64x64 tile / 256-thread block; 4 waves 2x2; wave = 2x2 of 16x16x32 frags.
// Explicit 2-deep K pipeline, #pragma unroll 1 (R5 structure, kept constant).
// ---------------------------------------------------------------------------
__global__ __launch_bounds__(256)
void gemm_kernel(const __hip_bfloat16* __restrict__ geB,
                 const __hip_bfloat16* __restrict__ gdB,
                 const __hip_bfloat16* __restrict__ WB,
                 float* __restrict__ encP,
                 float* __restrict__ decP) {
    int blk = blockIdx.x;
    const __hip_bfloat16* A;
    float* C;
    int M, kofs, mt, nt;
    if (blk < 256) {
        A = geB; C = encP; M = B_ * T_; kofs = 0;
        mt = blk >> 4; nt = blk & 15;
    } else {
        blk -= 256;
        A = gdB; C = decP; M = B_ * U_; kofs = D_;
        mt = blk >> 4; nt = blk & 15;
    }
    const int lane = threadIdx.x & 63;
    const int w    = threadIdx.x >> 6;     // 0..3
    const int wr   = w >> 1, wc = w & 1;   // waves 2x2 over the 64x64 tile
    const int r16  = lane & 15;            // A row / B col within fragment
    const int k8   = (lane >> 4) * 8;      // K sub-offset within K=32 step

    const int m_base = mt * 64 + wr * 32;
    const int n_base = nt * 64 + wc * 32;

    const __hip_bfloat16* Arow0 = A + (size_t)((m_base + 0  + r16) < M ? (m_base + 0  + r16) : 0) * D_ + k8;
    const __hip_bfloat16* Arow1 = A + (size_t)((m_base + 16 + r16) < M ? (m_base + 16 + r16) : 0) * D_ + k8;
    const __hip_bfloat16* Brow0 = WB + (size_t)(n_base + 0  + r16) * (2 * D_) + kofs + k8;
    const __hip_bfloat16* Brow1 = WB + (size_t)(n_base + 16 + r16) * (2 * D_) + kofs + k8;

    f32x4 acc[2][2] = {};
    bf16x8 aC0, aC1, bC0, bC1, aN0, aN1, bN0, bN1;

    aC0 = *(const bf16x8*)(Arow0);  aC1 = *(const bf16x8*)(Arow1);
    bC0 = *(const bf16x8*)(Brow0);  bC1 = *(const bf16x8*)(Brow1);

#pragma unroll 1
    for (int k0 = 0; k0 < D_; k0 += 64) {
        aN0 = *(const bf16x8*)(Arow0 + k0 + 32);
        aN1 = *(const bf16x8*)(Arow1 + k0 + 32);
        bN0 = *(const bf16x8*)(Brow0 + k0 + 32);
        bN1 = *(const bf16x8*)(Brow1 + k0 + 32);
        acc[0][0] = __builtin_amdgcn_mfma_f32_16x16x32_bf16(aC0, bC0, acc[0][0], 0, 0, 0);
        acc[0][1] = __builtin_amdgcn_mfma_f32_16x16x32_bf16(aC0, bC1, acc[0][1], 0, 0, 0);
        acc[1][0] = __builtin_amdgcn_mfma_f32_16x16x32_bf16(aC1, bC0, acc[1][0], 0, 0, 0);
        acc[1][1] = __builtin_amdgcn_mfma_f32_16x16x32_bf16(aC1, bC1, acc[1][1], 0, 0, 0);
        if (k0 + 64 < D_) {
            aC0 = *(const bf16x8*)(Arow0 + k0 + 64);
            aC1 = *(const bf16x8*)(Arow1 + k0 + 64);
            bC0 = *(const bf16x8*)(Brow0 + k0 + 64);
            bC1 = *(const bf16x8*)(Brow1 + k0 + 64);
        }
        acc[0][0] = __builtin_amdgcn_mfma_f32_16x16x32_bf16(aN0, bN0, acc[0][0], 0, 0, 0);
        acc[0][1] = __builtin_amdgcn_mfma_f32_16x16x32_bf16(aN0, bN1, acc[0][1], 0, 0, 0);
        acc[1][0] = __builtin_amdgcn_mfma_f32_16x16x32_bf16(aN1, bN0, acc[1][0], 0, 0, 0);
        acc[1][1] = __builtin_amdgcn_mfma_f32_16x16x32_bf16(aN1, bN1, acc[1][1], 0, 0, 0);
    }

    // C/D layout: col = lane&15, row = (lane>>4)*4 + j
    const int c_row0 = (lane >> 4) * 4;
#pragma unroll
    for (int mi = 0; mi < 2; ++mi) {
#pragma unroll
        for (int j = 0; j < 4; ++j) {
            int row = m_base + mi * 16 + c_row0 + j;
            if (row < M) {
#pragma unroll
                for (int ni = 0; ni < 2; ++ni) {
                    int col = n_base + ni * 16 + r16;
                    C[(size_t)row * V_ + col] = acc[mi][ni][j];
                }
            }
        }
    }
}

// ---------------------------------------------------------------------------
// Kernel 3: broadcast add — R9 structure, USPLIT 4->5: segments of exactly 13
// (65 = 5*13, no tail imbalance), grid (128,5) = 640 blocks = 2.5/CU for
// dynamic scheduling slack. Hoisted loads (13 dv + 8 ev), pure store phase,
// regular stores, i-outer store order (13 consecutive 4KB rows per stream).
// ---------------------------------------------------------------------------
__global__ __launch_bounds__(256)
void bcast_kernel(const float* __restrict__ encP,
                  const float* __restrict__ decP,
                  float* __restrict__ out) {
    const int tid = threadIdx.x;           // 256 threads * f32x4 = V=1024
    const int bt0 = blockIdx.x * TB;
    const int b   = bt0 >> 8;              // T_ = 256, TB | 256
    const int u0  = blockIdx.y * ULEN;

    const f32x4* d4 = (const f32x4*)(decP + (size_t)b * U_ * V_);

    // hoisted loads: 13 dv + 8 ev, all independent and in flight before stores
    f32x4 dv[ULEN];
#pragma unroll
    for (int j = 0; j < ULEN; ++j)
        dv[j] = d4[(size_t)(u0 + j) * (V_ / 4) + tid];

    f32x4 ev[TB];
#pragma unroll
    for (int i = 0; i < TB; ++i)
        ev[i] = ((const f32x4*)(encP + (size_t)(bt0 + i) * V_))[tid];

    f32x4* o4 = (f32x4*)(out + (size_t)bt0 * U_ * V_);

    // pure store phase: per (i) stream, 13 consecutive 4KB rows
#pragma unroll
    for (int i = 0; i < TB; ++i) {
#pragma unroll
        for (int j = 0; j < ULEN; ++j) {
            f32x4 ov = ev[i] + dv[j];
            o4[((size_t)i * U_ + (u0 + j)) * (V_ / 4) + tid] = ov;
        }
    }
}

extern "C" void kernel_launch(void* const* d_in, const int* in_sizes, int n_in,
                              void* d_out, int out_size, void* d_ws, size_t ws_size,
                              hipStream_t stream) {
    const float* enc = (const float*)d_in[0];   // (4,256,512)
    const float* dec = (const float*)d_in[1];   // (4,65,512)
    const float* W   = (const float*)d_in[2];   // (1024, 1024)
    float* out = (float*)d_out;                 // (4,256,65,1024)

    char* ws = (char*)d_ws;
    __hip_bfloat16* geB  = (__hip_bfloat16*)(ws);              // 1.00 MB
    __hip_bfloat16* gdB  = (__hip_bfloat16*)(ws + 0x100000);   // 0.26 MB
    __hip_bfloat16* WB   = (__hip_bfloat16*)(ws + 0x180000);   // 2.00 MB
    float*          encP = (float*)(ws + 0x380000);            // 4.00 MB
    float*          decP = (float*)(ws + 0x780000);            // 1.04 MB

    const int total4 = (B_ * T_ * D_ + B_ * U_ * D_ + V_ * 2 * D_) / 4;  // 426496
    prep_kernel<<<(total4 + 255) / 256, 256, 0, stream>>>(enc, dec, W, geB, gdB, WB);
    gemm_kernel<<<256 + 80, 256, 0, stream>>>(geB, gdB, WB, encP, decP);
    dim3 bgrid((B_ * T_) / TB, USPLIT);  // (128, 5) = 640 blocks
    bcast_kernel<<<bgrid, 256, 0, stream>>>(encP, decP, out);
}